// Round 1
// 151070.337 us; speedup vs baseline: 1.4450x; 1.4450x over previous
//
#include <hip/hip_runtime.h>

#define AGENT __HIP_MEMORY_SCOPE_AGENT
typedef unsigned int u32;
typedef unsigned long long u64;

constexpr int TSTEPS = 16384;
constexpr float INV_BINS    = 1.0f / 127.5f;
constexpr float INIT_SCALED = 128.0f * (1.0f / 127.5f) - 1.0f;
constexpr int REP = 4;   // replicas of the tagged h vector

// ---- workspace layout: tagged u64 slots [tag:32 | f32 bits:32] -------------
// HT : ((par*2+half)*REP + rep)*448 + idx   h(t) values, 4 replicas   114688 B
// HPT: (par*2+half)*1344 + row              hp rows (Wh@h + bh)        43008 B
// PL : ((par*2+half)*16 + oid)*256 + row    partial logits            131072 B
constexpr int HT_OFF  = 0;
constexpr int HPT_OFF = 114688;
constexpr int PL_OFF  = 157696;   // end of workspace use: 288768 B

__device__ __forceinline__ u64  ld64(const u64* p){ return __hip_atomic_load((u64*)p, __ATOMIC_RELAXED, AGENT); }
__device__ __forceinline__ void st64(u64* p, u64 v){ __hip_atomic_store(p, v, __ATOMIC_RELAXED, AGENT); }

__device__ __forceinline__ float wave_sum(float s) {
  #pragma unroll
  for (int d = 1; d < 64; d <<= 1) s += __shfl_xor(s, d, 64);
  return s;
}
__device__ __forceinline__ u64 u64max(u64 a, u64 b) { return a > b ? a : b; }
__device__ __forceinline__ u64 wave_max64(u64 v) {
  #pragma unroll
  for (int d = 1; d < 64; d <<= 1) v = u64max(v, __shfl_xor(v, d, 64));
  return v;
}
__device__ __forceinline__ float sigf(float x) { return 1.0f / (1.0f + __expf(-x)); }
__device__ __forceinline__ u64  tagf(u32 tg, float x) { return ((u64)tg << 32) | (u64)__float_as_uint(x); }
__device__ __forceinline__ u32  tago(u64 v) { return (u32)(v >> 32); }
__device__ __forceinline__ float valf(u64 v) { return __uint_as_float((u32)(v & 0xFFFFFFFFull)); }

// argmax key: monotone f32 in bits [39:8], (255-row) in [7:0]; u64max == first-max argmax
__device__ __forceinline__ u64 amkey(float x, int row) {
  u32 u = __float_as_uint(x);
  u = (u & 0x80000000u) ? ~u : (u | 0x80000000u);
  return ((u64)u << 8) | (u64)(u32)(255 - row);
}
__device__ __forceinline__ int amrow(u64 k) { return 255 - (int)(k & 0xFFull); }

extern "C" __global__ void __launch_bounds__(256, 1)
wavernn_persist(const float* __restrict__ Wh,  const float* __restrict__ bh,
                const float* __restrict__ Wci, const float* __restrict__ Wfi,
                const float* __restrict__ cbias, const float* __restrict__ fbias,
                const float* __restrict__ pWc, const float* __restrict__ pBc,
                const float* __restrict__ bWc, const float* __restrict__ bBc,
                const float* __restrict__ pWf, const float* __restrict__ pBf,
                const float* __restrict__ bWf, const float* __restrict__ bBf,
                const float* __restrict__ h0,
                float* __restrict__ out, char* __restrict__ wsb)
{
  const int tid  = threadIdx.x;
  const int lane = tid & 63;
  const int wv   = tid >> 6;
  const int wg   = blockIdx.x;

  u64* HT  = (u64*)(wsb + HT_OFF);
  u64* HPT = (u64*)(wsb + HPT_OFF);
  u64* PL  = (u64*)(wsb + PL_OFF);

  if (wg < 32) {
    // ============ output WGs: coarse 0-15, fine 16-31 =======================
    const int half = wg >> 4;
    const int oid  = wg & 15;
    const int ncol = half ? 3 : 2;
    const float* Wi  = half ? Wfi : Wci;
    const float* tbp = half ? fbias : cbias;
    const float* pW  = half ? pWf : pWc;
    const float* pB  = half ? pBf : pBc;
    const float* bW  = half ? bWf : bWc;
    const float* bB  = half ? bBf : bBc;

    const int u1 = tid;                 // gate unit 1 (0..255)
    const bool hasB = (tid < 192);
    const int u2 = 256 + tid;           // gate unit 2 (256..447)

    float wiA[3][3], wiB[3][3];
    #pragma unroll
    for (int g = 0; g < 3; ++g)
      #pragma unroll
      for (int c = 0; c < 3; ++c) {
        wiA[g][c] = (c < ncol) ? Wi[(g * 448 + u1) * ncol + c] : 0.0f;
        wiB[g][c] = (hasB && c < ncol) ? Wi[(g * 448 + u2) * ncol + c] : 0.0f;
      }
    float hvA = h0[half * 448 + u1];
    float hvB = hasB ? h0[half * 448 + u2] : 0.0f;

    // pre rows owned by this WG: oid*28 + wv*7 + r  (28 rows per WG, in LDS only)
    float wpre[7][7], bpre[7];
    #pragma unroll
    for (int r = 0; r < 7; ++r) {
      const int row = oid * 28 + wv * 7 + r;
      #pragma unroll
      for (int k = 0; k < 7; ++k) wpre[r][k] = pW[row * 448 + k * 64 + lane];
      bpre[r] = pB[row];
    }
    // bin weights: thread owns bin row 'tid', the 28 k-columns this WG's pre covers
    float wbin[28];
    #pragma unroll
    for (int j = 0; j < 28; ++j) wbin[j] = bW[tid * 448 + oid * 28 + j];
    const float bbin = (oid == 0) ? bB[tid] : 0.0f;   // bias folded into partial 0

    __shared__ float sh[448];
    __shared__ float spre[28];
    __shared__ u64 smA[4], smB[4], smX[4];

    for (int t = 0; t < TSTEPS; ++t) {
      const int par = t & 1;
      const u32 tg  = (u32)(t + 1);

      // per-step bias prefetch (HBM latency hides under the polls)
      float tbA[3], tbB[3];
      #pragma unroll
      for (int g = 0; g < 3; ++g) {
        tbA[g] = tbp[(size_t)t * 1344 + g * 448 + u1];
        tbB[g] = hasB ? tbp[(size_t)t * 1344 + g * 448 + u2] : 0.0f;
      }

      // ---- prev samples: reduce PL(t-1) of both halves (data long ready) ---
      float c_prev, f_prev;
      if (t >= 1) {
        const int parp = par ^ 1;
        const u64* plc = PL + (size_t)((parp * 2 + 0) * 16) * 256 + tid;
        const u64* plf = PL + (size_t)((parp * 2 + 1) * 16) * 256 + tid;
        float sc = 0.f, sf = 0.f;
        for (;;) {
          u64 vc[16], vf[16]; bool ok = true;
          #pragma unroll
          for (int o = 0; o < 16; ++o) { vc[o] = ld64(plc + o * 256); ok &= (tago(vc[o]) == (u32)t); }
          #pragma unroll
          for (int o = 0; o < 16; ++o) { vf[o] = ld64(plf + o * 256); ok &= (tago(vf[o]) == (u32)t); }
          if (__all(ok)) {
            sc = 0.f; sf = 0.f;
            #pragma unroll
            for (int o = 0; o < 16; ++o) { sc += valf(vc[o]); sf += valf(vf[o]); }
            break;
          }
        }
        const u64 kc = wave_max64(amkey(sc, tid));
        const u64 kf = wave_max64(amkey(sf, tid));
        if (lane == 0) { smA[wv] = kc; smB[wv] = kf; }
        __syncthreads();
        const u64 mc = u64max(u64max(smA[0], smA[1]), u64max(smA[2], smA[3]));
        const u64 mf = u64max(u64max(smB[0], smB[1]), u64max(smB[2], smB[3]));
        c_prev = (float)amrow(mc) * INV_BINS - 1.0f;
        f_prev = (float)amrow(mf) * INV_BINS - 1.0f;
        if (!half && oid == 0 && tid == 0) out[TSTEPS + t - 1] = (float)amrow(mf);
      } else {
        c_prev = INIT_SCALED; f_prev = INIT_SCALED;
      }

      // ---- hp poll: each thread waits only on its own 3(6) tagged rows -----
      const u64* hpt = HPT + (size_t)(par * 2 + half) * 1344;
      float hpA[3], hpB[3];
      for (;;) {
        u64 a0 = ld64(hpt + u1), a1 = ld64(hpt + 448 + u1), a2 = ld64(hpt + 896 + u1);
        u64 b0 = 0, b1 = 0, b2 = 0;
        bool ok = (tago(a0) == tg) && (tago(a1) == tg) && (tago(a2) == tg);
        if (hasB) {
          b0 = ld64(hpt + u2); b1 = ld64(hpt + 448 + u2); b2 = ld64(hpt + 896 + u2);
          ok &= (tago(b0) == tg) && (tago(b1) == tg) && (tago(b2) == tg);
        }
        if (__all(ok)) {
          hpA[0] = valf(a0); hpA[1] = valf(a1); hpA[2] = valf(a2);
          hpB[0] = valf(b0); hpB[1] = valf(b1); hpB[2] = valf(b2);
          break;
        }
      }

      // ---- gate pre-activations (input-weight part) ------------------------
      float in2A[3], in2B[3];
      if (!half) {
        #pragma unroll
        for (int g = 0; g < 3; ++g) {
          in2A[g] = fmaf(wiA[g][1], f_prev, fmaf(wiA[g][0], c_prev, tbA[g]));
          in2B[g] = fmaf(wiB[g][1], f_prev, fmaf(wiB[g][0], c_prev, tbB[g]));
        }
      } else {
        // fine: hot wait on coarse PL(t), reduce in-WG to get c(t)
        const u64* plc = PL + (size_t)((par * 2 + 0) * 16) * 256 + tid;
        float sc2;
        for (;;) {
          u64 v[16]; bool ok = true;
          #pragma unroll
          for (int o = 0; o < 16; ++o) { v[o] = ld64(plc + o * 256); ok &= (tago(v[o]) == tg); }
          if (__all(ok)) {
            sc2 = 0.f;
            #pragma unroll
            for (int o = 0; o < 16; ++o) sc2 += valf(v[o]);
            break;
          }
        }
        const u64 k = wave_max64(amkey(sc2, tid));
        if (lane == 0) smX[wv] = k;
        __syncthreads();
        const u64 m = u64max(u64max(smX[0], smX[1]), u64max(smX[2], smX[3]));
        const int cbin = amrow(m);
        const float csc = (float)cbin * INV_BINS - 1.0f;
        if (oid == 0 && tid == 0) out[t] = (float)cbin;
        #pragma unroll
        for (int g = 0; g < 3; ++g) {
          in2A[g] = fmaf(wiA[g][2], csc, fmaf(wiA[g][1], f_prev, fmaf(wiA[g][0], c_prev, tbA[g])));
          in2B[g] = fmaf(wiB[g][2], csc, fmaf(wiB[g][1], f_prev, fmaf(wiB[g][0], c_prev, tbB[g])));
        }
      }

      // ---- GRU cell, publish tagged h (replicas 0..REP-1) ------------------
      {
        const float r = sigf(in2A[0] + hpA[0]);
        const float u = sigf(in2A[1] + hpA[1]);
        const float n = tanhf(in2A[2] + r * hpA[2]);
        hvA = u * (hvA - n) + n;
        sh[u1] = hvA;
        if (oid < REP) st64(HT + ((size_t)((par * 2 + half) * REP + oid)) * 448 + u1, tagf(tg, hvA));
      }
      if (hasB) {
        const float r = sigf(in2B[0] + hpB[0]);
        const float u = sigf(in2B[1] + hpB[1]);
        const float n = tanhf(in2B[2] + r * hpB[2]);
        hvB = u * (hvB - n) + n;
        sh[u2] = hvB;
        if (oid < REP) st64(HT + ((size_t)((par * 2 + half) * REP + oid)) * 448 + u2, tagf(tg, hvB));
      }
      __syncthreads();                                   // B3: sh complete

      // ---- pre rows (LDS only, never published) ----------------------------
      {
        float hv7[7];
        #pragma unroll
        for (int k = 0; k < 7; ++k) hv7[k] = sh[k * 64 + lane];
        #pragma unroll
        for (int r = 0; r < 7; ++r) {
          float s = 0.f;
          #pragma unroll
          for (int k = 0; k < 7; ++k) s = fmaf(wpre[r][k], hv7[k], s);
          s = fmaxf(wave_sum(s) + bpre[r], 0.f);
          if (lane == 0) spre[wv * 7 + r] = s;
        }
      }
      __syncthreads();                                   // B4: spre complete

      // ---- partial logit per bin row, publish tagged -----------------------
      {
        float pl = bbin;
        #pragma unroll
        for (int j = 0; j < 28; ++j) pl = fmaf(wbin[j], spre[j], pl);
        st64(PL + ((size_t)((par * 2 + half) * 16 + oid)) * 256 + tid, tagf(tg, pl));
      }
    }

    // ---- epilogue: f(16383) from fine PL, and final hidden state -----------
    if (!half && oid == 0) {
      const u64* plf = PL + (size_t)((1 * 2 + 1) * 16) * 256 + tid;  // par=1, fine
      float sf;
      for (;;) {
        u64 v[16]; bool ok = true;
        #pragma unroll
        for (int o = 0; o < 16; ++o) { v[o] = ld64(plf + o * 256); ok &= (tago(v[o]) == 16384u); }
        if (__all(ok)) {
          sf = 0.f;
          #pragma unroll
          for (int o = 0; o < 16; ++o) sf += valf(v[o]);
          break;
        }
      }
      const u64 k = wave_max64(amkey(sf, tid));
      if (lane == 0) smA[wv] = k;
      __syncthreads();
      if (tid == 0)
        out[2 * TSTEPS - 1] =
            (float)amrow(u64max(u64max(smA[0], smA[1]), u64max(smA[2], smA[3])));
    }
    if (oid == 0) {
      out[2 * TSTEPS + half * 448 + u1] = hvA;
      if (hasB) out[2 * TSTEPS + half * 448 + u2] = hvB;
    }

  } else {
    // =================== hp WGs: coarse 32-73, fine 74-115 ==================
    const int id   = wg - 32;
    const int half = (id >= 42) ? 1 : 0;
    const int wgl  = id - 42 * half;          // 0..41
    const int r0   = (wgl * 4 + wv) * 8;      // first of 8 owned rows
    const int rep  = wg & (REP - 1);          // which h replica to poll

    float wh[8][14], hb[8];
    #pragma unroll
    for (int j = 0; j < 8; ++j) {
      const int grow = half * 1344 + r0 + j;
      #pragma unroll
      for (int k = 0; k < 14; ++k) wh[j][k] = Wh[(size_t)grow * 896 + k * 64 + lane];
      hb[j] = bh[grow];
    }

    for (int t = 0; t < TSTEPS; ++t) {
      const int par = t & 1;
      const u32 tg  = (u32)(t + 1);
      float s[8];

      if (t == 0) {
        float hv[14];
        #pragma unroll
        for (int k = 0; k < 14; ++k) hv[k] = h0[k * 64 + lane];
        #pragma unroll
        for (int j = 0; j < 8; ++j) {
          float a = 0.f;
          #pragma unroll
          for (int k = 0; k < 14; ++k) a = fmaf(wh[j][k], hv[k], a);
          s[j] = a;
        }
      } else {
        const u32 tp = (u32)t;                // tag of h(t-1)
        const int p2 = (par ^ 1) * 2;
        const u64* hc = HT + ((size_t)((p2 + 0) * REP + rep)) * 448 + lane;
        const u64* hf = HT + ((size_t)((p2 + 1) * REP + rep)) * 448 + lane;
        // coarse half arrives early: partial sums first
        {
          float hv[7];
          for (;;) {
            u64 v[7]; bool ok = true;
            #pragma unroll
            for (int k = 0; k < 7; ++k) { v[k] = ld64(hc + k * 64); ok &= (tago(v[k]) == tp); }
            if (__all(ok)) {
              #pragma unroll
              for (int k = 0; k < 7; ++k) hv[k] = valf(v[k]);
              break;
            }
          }
          #pragma unroll
          for (int j = 0; j < 8; ++j) {
            float a = 0.f;
            #pragma unroll
            for (int k = 0; k < 7; ++k) a = fmaf(wh[j][k], hv[k], a);
            s[j] = a;
          }
        }
        // fine half: cheap 1-slot sentinel spin, then full verify (cuts poll traffic 7x)
        for (;;) { u64 sv = ld64(hf + 384); if (__all(tago(sv) == tp)) break; }
        {
          float hv[7];
          for (;;) {
            u64 v[7]; bool ok = true;
            #pragma unroll
            for (int k = 0; k < 7; ++k) { v[k] = ld64(hf + k * 64); ok &= (tago(v[k]) == tp); }
            if (__all(ok)) {
              #pragma unroll
              for (int k = 0; k < 7; ++k) hv[k] = valf(v[k]);
              break;
            }
          }
          #pragma unroll
          for (int j = 0; j < 8; ++j) {
            float a = s[j];
            #pragma unroll
            for (int k = 0; k < 7; ++k) a = fmaf(wh[j][k + 7], hv[k], a);
            s[j] = a;
          }
        }
      }

      // publish tagged hp rows directly (no barrier, no flags)
      u64* hp = HPT + (size_t)(par * 2 + half) * 1344 + r0;
      #pragma unroll
      for (int j = 0; j < 8; ++j) {
        const float a = wave_sum(s[j]) + hb[j];
        if (lane == 0) st64(hp + j, tagf(tg, a));
      }
    }
  }
}

extern "C" void kernel_launch(void* const* d_in, const int* in_sizes, int n_in,
                              void* d_out, int out_size, void* d_ws, size_t ws_size,
                              hipStream_t stream) {
  (void)in_sizes; (void)n_in; (void)out_size; (void)ws_size;
  wavernn_persist<<<116, 256, 0, stream>>>(
      (const float*)d_in[0],  (const float*)d_in[1],  (const float*)d_in[2],
      (const float*)d_in[3],  (const float*)d_in[4],  (const float*)d_in[5],
      (const float*)d_in[6],  (const float*)d_in[7],  (const float*)d_in[8],
      (const float*)d_in[9],  (const float*)d_in[10], (const float*)d_in[11],
      (const float*)d_in[12], (const float*)d_in[13], (const float*)d_in[14],
      (float*)d_out, (char*)d_ws);
}